// Round 10
// baseline (589.624 us; speedup 1.0000x reference)
//
#include <hip/hip_runtime.h>
#include <hip/hip_bf16.h>
#include <hip/hip_fp16.h>
#include <math.h>

constexpr int B = 2;
constexpr int N = 5000;
constexpr int C = 256;
constexpr int H = 8;
constexpr int DK = 32;
constexpr int M = 2500;
constexpr int MP = 2512;            // padded V stride (16-elem multiple)
constexpr int KSTEPS = 157;         // ceil(5000/32)
constexpr int SPLIT = 8;            // conv split-K (== XCD count)
constexpr int MTILES = 79;          // ceil(2500/32)
constexpr float QSCALE = 0.2550598692503365f;        // (1/sqrt(32)) * log2(e)

typedef __attribute__((ext_vector_type(8))) short bf16x8;
typedef __attribute__((ext_vector_type(4))) float f32x4;
typedef __fp16 h16x2 __attribute__((ext_vector_type(2)));
typedef _Float16 f16x4 __attribute__((ext_vector_type(4)));

static __device__ __forceinline__ ushort f2bf(float f) {
  __hip_bfloat16 h = __float2bfloat16(f);
  return *reinterpret_cast<ushort*>(&h);
}

static __device__ __forceinline__ float fastexp2(float x) {
#if __has_builtin(__builtin_amdgcn_exp2f)
  return __builtin_amdgcn_exp2f(x);
#else
  return exp2f(x);
#endif
}

// ---------------------------------------------------------------------------
// K0a: cast Wq|Wk|Wv fp32 -> bf16 into W16[3][C][C]
// ---------------------------------------------------------------------------
__global__ __launch_bounds__(256) void wcast(const float* __restrict__ Wq,
                                             const float* __restrict__ Wk,
                                             const float* __restrict__ Wv,
                                             ushort* __restrict__ W16) {
  const float* src = (blockIdx.y == 0) ? Wq : (blockIdx.y == 1) ? Wk : Wv;
  const int idx = blockIdx.x * 1024 + threadIdx.x * 4;
  const float4 v = *reinterpret_cast<const float4*>(src + idx);
  ushort4 o;
  o.x = f2bf(v.x); o.y = f2bf(v.y); o.z = f2bf(v.z); o.w = f2bf(v.w);
  *reinterpret_cast<ushort4*>(W16 + (size_t)blockIdx.y * C * C + idx) = o;
}

// ---------------------------------------------------------------------------
// K0b: x fp32 -> xTt[b][ks][c][32] bf16 (k-step-blocked, zero pad) AND xb16[b][n][c]
// ---------------------------------------------------------------------------
__global__ __launch_bounds__(256) void xt_cast(const float* __restrict__ x,
                                               ushort* __restrict__ xTt,
                                               ushort* __restrict__ xb16) {
  const int n0 = blockIdx.x * 64, c0 = blockIdx.y * 64, b = blockIdx.z;
  const int tid = threadIdx.x;
  __shared__ ushort T[64][68];  // [n][c]
  const float* xb = x + (size_t)b * N * C;
#pragma unroll
  for (int i = 0; i < 4; ++i) {
    const int nl = (tid >> 4) + i * 16;
    const int cg = (tid & 15) * 4;
    float4 v = {0.f, 0.f, 0.f, 0.f};
    const bool ok = (n0 + nl) < N;
    if (ok) v = *reinterpret_cast<const float4*>(xb + (size_t)(n0 + nl) * C + c0 + cg);
    ushort4 u;
    u.x = f2bf(v.x); u.y = f2bf(v.y); u.z = f2bf(v.z); u.w = f2bf(v.w);
    T[nl][cg + 0] = u.x; T[nl][cg + 1] = u.y; T[nl][cg + 2] = u.z; T[nl][cg + 3] = u.w;
    if (ok)
      *reinterpret_cast<ushort4*>(xb16 + ((size_t)b * N + n0 + nl) * C + c0 + cg) = u;
  }
  __syncthreads();
  ushort* ob = xTt + (size_t)b * KSTEPS * C * 32;
  const int cl = tid & 63, ng = tid >> 6;
#pragma unroll
  for (int j = 0; j < 2; ++j) {
    const int nstart = ng * 16 + j * 8;   // 0,8,...,56
    const int n = n0 + nstart;
    if (n >= KSTEPS * 32) continue;
    const int ks = n >> 5, kk = n & 31;
    ushort vals[8];
#pragma unroll
    for (int jj = 0; jj < 8; ++jj) vals[jj] = T[nstart + jj][cl];
    *reinterpret_cast<bf16x8*>(ob + ((size_t)ks * C + (c0 + cl)) * 32 + kk) =
        *reinterpret_cast<const bf16x8*>(vals);
  }
}

// ---------------------------------------------------------------------------
// K1: conv via MFMA — coalesced direct-load, merged batch, XCD-affine split-K.
// ---------------------------------------------------------------------------
__global__ __launch_bounds__(256) void conv_mfma(const float* __restrict__ Wc,
                                                 const ushort* __restrict__ xTt,
                                                 ushort* __restrict__ xpart) {
  const int s = blockIdx.x & 7;
  const int mt = blockIdx.x >> 3;
  const int m0 = mt * 32;
  const int tid = threadIdx.x, w = tid >> 6, l = tid & 63;
  const int lr = l & 15, lg = l >> 4;
  f32x4 acc[16];
#pragma unroll
  for (int i = 0; i < 16; ++i) acc[i] = (f32x4){0.f, 0.f, 0.f, 0.f};
  const int row0 = m0 + lr, row1 = m0 + 16 + lr;
  const bool ok0 = row0 < M, ok1 = row1 < M;
  const float* ap0 = Wc + (size_t)(ok0 ? row0 : 0) * N + lg * 8;
  const float* ap1 = Wc + (size_t)(ok1 ? row1 : 0) * N + lg * 8;
  const int crow = w * 64 + lr;

#pragma unroll 2
  for (int ks = s; ks < KSTEPS; ks += SPLIT) {
    const int n0 = ks * 32;
    const bool kok = (n0 + lg * 8) < N;
    bf16x8 a0 = {0, 0, 0, 0, 0, 0, 0, 0}, a1 = {0, 0, 0, 0, 0, 0, 0, 0};
    if (ok0 && kok) {
      const float4 v0 = *reinterpret_cast<const float4*>(ap0 + n0);
      const float4 v1 = *reinterpret_cast<const float4*>(ap0 + n0 + 4);
      ushort u[8];
      u[0] = f2bf(v0.x); u[1] = f2bf(v0.y); u[2] = f2bf(v0.z); u[3] = f2bf(v0.w);
      u[4] = f2bf(v1.x); u[5] = f2bf(v1.y); u[6] = f2bf(v1.z); u[7] = f2bf(v1.w);
      a0 = *reinterpret_cast<const bf16x8*>(u);
    }
    if (ok1 && kok) {
      const float4 v0 = *reinterpret_cast<const float4*>(ap1 + n0);
      const float4 v1 = *reinterpret_cast<const float4*>(ap1 + n0 + 4);
      ushort u[8];
      u[0] = f2bf(v0.x); u[1] = f2bf(v0.y); u[2] = f2bf(v0.z); u[3] = f2bf(v0.w);
      u[4] = f2bf(v1.x); u[5] = f2bf(v1.y); u[6] = f2bf(v1.z); u[7] = f2bf(v1.w);
      a1 = *reinterpret_cast<const bf16x8*>(u);
    }
    bf16x8 bf[8];
#pragma unroll
    for (int ct = 0; ct < 4; ++ct)
#pragma unroll
      for (int bb = 0; bb < 2; ++bb)
        bf[ct * 2 + bb] = *reinterpret_cast<const bf16x8*>(
            xTt + (((size_t)bb * KSTEPS + ks) * C + crow + ct * 16) * 32 + lg * 8);
#pragma unroll
    for (int ct = 0; ct < 4; ++ct)
#pragma unroll
      for (int bb = 0; bb < 2; ++bb) {
        acc[(0 * 4 + ct) * 2 + bb] =
            __builtin_amdgcn_mfma_f32_16x16x32_bf16(a0, bf[ct * 2 + bb], acc[(0 * 4 + ct) * 2 + bb], 0, 0, 0);
        acc[(1 * 4 + ct) * 2 + bb] =
            __builtin_amdgcn_mfma_f32_16x16x32_bf16(a1, bf[ct * 2 + bb], acc[(1 * 4 + ct) * 2 + bb], 0, 0, 0);
      }
  }

#pragma unroll
  for (int mf = 0; mf < 2; ++mf)
#pragma unroll
    for (int ct = 0; ct < 4; ++ct)
#pragma unroll
      for (int bb = 0; bb < 2; ++bb)
#pragma unroll
        for (int i = 0; i < 4; ++i) {
          const int m = m0 + mf * 16 + lg * 4 + i;
          if (m < M) {
            const __half hv = __float2half(acc[(mf * 4 + ct) * 2 + bb][i]);
            xpart[(((size_t)s * B + bb) * M + m) * C + w * 64 + ct * 16 + lr] =
                *reinterpret_cast<const ushort*>(&hv);
          }
        }
}

// ---------------------------------------------------------------------------
// K2: sum SPLIT fp16 partials + bc + LayerNorm -> bf16 row-major xr16
// ---------------------------------------------------------------------------
__global__ __launch_bounds__(256) void ln_kernel(const ushort* __restrict__ xp,
                                                 const float* __restrict__ bc,
                                                 const float* __restrict__ gamma,
                                                 const float* __restrict__ beta,
                                                 ushort* __restrict__ xr16) {
  const int row = blockIdx.x;  // b*M + m
  const int tid = threadIdx.x;
  const int b = row / M, m = row - b * M;
  const size_t base = (size_t)row * C;
  float v = bc[m];
#pragma unroll
  for (int s = 0; s < SPLIT; ++s) {
    const ushort us = xp[(((size_t)s * B + b) * M + m) * C + tid];
    v += __half2float(*reinterpret_cast<const __half*>(&us));
  }
  __shared__ float red[8];
  float sum = v;
#pragma unroll
  for (int o = 32; o >= 1; o >>= 1) sum += __shfl_xor(sum, o);
  if ((tid & 63) == 0) red[tid >> 6] = sum;
  __syncthreads();
  const float mu = (red[0] + red[1] + red[2] + red[3]) * (1.f / C);
  const float d = v - mu;
  float s2 = d * d;
#pragma unroll
  for (int o = 32; o >= 1; o >>= 1) s2 += __shfl_xor(s2, o);
  if ((tid & 63) == 0) red[4 + (tid >> 6)] = s2;
  __syncthreads();
  const float var = (red[4] + red[5] + red[6] + red[7]) * (1.f / C);
  xr16[base + tid] = f2bf(gamma[tid] * d * rsqrtf(var + 1e-5f) + beta[tid]);
}

// ---------------------------------------------------------------------------
// K3: projections via MFMA. grid.z: 0=Q(xb16, scale=QSCALE incl log2e), 1=K(xr16),
// 2=V^T(xr16, stored FP16 d-major stride MP — feeds PV's 16x16x16 f16 MFMA).
// ---------------------------------------------------------------------------
__global__ __launch_bounds__(256) void proj_all(const ushort* __restrict__ xb16,
                                                const ushort* __restrict__ xr16,
                                                const ushort* __restrict__ W16,
                                                const float* __restrict__ bq,
                                                const float* __restrict__ bk,
                                                const float* __restrict__ bv,
                                                ushort* __restrict__ qb,
                                                ushort* __restrict__ kb,
                                                ushort* __restrict__ vt) {
  const int z = blockIdx.z;
  const int R = (z == 0) ? N : M;
  const int totalRows = B * R;
  if (blockIdx.x * 64 >= totalRows) return;
  const ushort* xin = (z == 0) ? xb16 : xr16;
  const ushort* W = W16 + (size_t)z * C * C;
  const float* bias = (z == 0) ? bq : (z == 1) ? bk : bv;
  const int tid = threadIdx.x, w = tid >> 6, l = tid & 63;
  const int lr = l & 15, lg = l >> 4;
  const int r0 = blockIdx.x * 64 + w * 16;
  const int c0 = blockIdx.y * 64;
  const int arow = r0 + lr;
  const bool aok = arow < totalRows;
  f32x4 acc[4] = {{0.f,0.f,0.f,0.f},{0.f,0.f,0.f,0.f},{0.f,0.f,0.f,0.f},{0.f,0.f,0.f,0.f}};
#pragma unroll
  for (int ks = 0; ks < 8; ++ks) {
    bf16x8 af = {0, 0, 0, 0, 0, 0, 0, 0};
    if (aok) af = *reinterpret_cast<const bf16x8*>(xin + (size_t)arow * C + ks * 32 + lg * 8);
#pragma unroll
    for (int ct = 0; ct < 4; ++ct) {
      const bf16x8 bf =
          *reinterpret_cast<const bf16x8*>(W + (size_t)(c0 + ct * 16 + lr) * C + ks * 32 + lg * 8);
      acc[ct] = __builtin_amdgcn_mfma_f32_16x16x32_bf16(af, bf, acc[ct], 0, 0, 0);
    }
  }
#pragma unroll
  for (int ct = 0; ct < 4; ++ct) {
    const int c = c0 + ct * 16 + lr;
    const int h = c >> 5, d = c & 31;
    const float bi = bias[c];
#pragma unroll
    for (int i = 0; i < 4; ++i) {
      const int row = r0 + lg * 4 + i;
      if (row >= totalRows) continue;
      const int bb = (row >= R) ? 1 : 0;
      const int rr = row - bb * R;
      float val = acc[ct][i] + bi;
      if (z == 0) {
        val *= QSCALE;
        qb[(((size_t)bb * H + h) * N + rr) * DK + d] = f2bf(val);
      } else if (z == 1) {
        kb[(((size_t)bb * H + h) * M + rr) * DK + d] = f2bf(val);
      } else {
        const __half hv = __float2half(val);
        vt[(((size_t)bb * H + h) * DK + d) * MP + rr] = *reinterpret_cast<const ushort*>(&hv);
      }
    }
  }
}

// ---------------------------------------------------------------------------
// K4: register-chained flash attention. Swapped QK^T (mfma(K,Q)) gives lane:
// q = l&15, m = ct*16 + (l>>4)*4 + i — which is EXACTLY the A-fragment layout
// of mfma_f32_16x16x16 (row=l&15, k=(l>>4)*4+i). exp2 output feeds PV directly:
// no LDS, no shuffles, no barriers. V stored fp16 d-major; PV = 8x 16x16x16 f16.
// Single pass over 39 full tiles + masked tail; normalized write to out.
// ---------------------------------------------------------------------------
template <bool TAIL>
static __device__ __forceinline__ void attn_tile(const bf16x8 (&kf)[4], const bf16x8& qf,
                                                 const f16x4 (&vf)[8], f32x4 (&O)[2],
                                                 float& psum, int lg, int mlim) {
  f32x4 s[4];
#pragma unroll
  for (int ct = 0; ct < 4; ++ct)
    s[ct] = __builtin_amdgcn_mfma_f32_16x16x32_bf16(kf[ct], qf, (f32x4){0.f, 0.f, 0.f, 0.f}, 0, 0, 0);
#pragma unroll
  for (int ct = 0; ct < 4; ++ct) {
    float pv[4];
#pragma unroll
    for (int i = 0; i < 4; ++i) {
      float e = fastexp2(s[ct][i]);
      if (TAIL) {
        if (ct * 16 + lg * 4 + i >= mlim) e = 0.f;
      }
      pv[i] = e;
      psum += e;
    }
    union {
      h16x2 h2[2];
      f16x4 v;
    } pk;
    pk.h2[0] = __builtin_amdgcn_cvt_pkrtz(pv[0], pv[1]);
    pk.h2[1] = __builtin_amdgcn_cvt_pkrtz(pv[2], pv[3]);
    const f16x4 pa = pk.v;
#pragma unroll
    for (int dt = 0; dt < 2; ++dt)
      O[dt] = __builtin_amdgcn_mfma_f32_16x16x16f16(pa, vf[ct * 2 + dt], O[dt], 0, 0, 0);
  }
}

__global__ __launch_bounds__(256) void attn5(const ushort* __restrict__ q,
                                             const ushort* __restrict__ kk,
                                             const ushort* __restrict__ vt,
                                             float* __restrict__ out) {
  const int qt = blockIdx.x, h = blockIdx.y, b = blockIdx.z;
  const int tid = threadIdx.x, w = tid >> 6, l = tid & 63;
  const int lr = l & 15, lg = l >> 4;
  const int n0 = qt * 64 + w * 16;
  const ushort* qp = q + (size_t)(b * H + h) * N * DK;
  const ushort* kp = kk + (size_t)(b * H + h) * M * DK;
  const _Float16* vp = (const _Float16*)vt + (size_t)(b * H + h) * DK * MP;

  bf16x8 qf = {0, 0, 0, 0, 0, 0, 0, 0};
  if (n0 + lr < N) qf = *reinterpret_cast<const bf16x8*>(qp + (size_t)(n0 + lr) * DK + lg * 8);

  f32x4 O[2] = {{0.f, 0.f, 0.f, 0.f}, {0.f, 0.f, 0.f, 0.f}};
  float psum = 0.f;

  constexpr int NFULL = M / 64;  // 39
  bf16x8 kf[4];
#pragma unroll
  for (int ct = 0; ct < 4; ++ct)
    kf[ct] = *reinterpret_cast<const bf16x8*>(kp + (size_t)(ct * 16 + lr) * DK + lg * 8);

#pragma unroll 2
  for (int t = 0; t < NFULL; ++t) {
    const int m0 = t * 64;
    // next-tile K prefetch (clamped on last full tile; tail has its own guarded loads)
    const int tn = (t + 1 < NFULL) ? t + 1 : t;
    bf16x8 kn[4];
#pragma unroll
    for (int ct = 0; ct < 4; ++ct)
      kn[ct] = *reinterpret_cast<const bf16x8*>(kp + (size_t)(tn * 64 + ct * 16 + lr) * DK + lg * 8);
    // V fragments for this tile: vf[ct][dt] = V[m0+ct*16+lg*4 .. +3][dt*16+lr]
    f16x4 vf[8];
#pragma unroll
    for (int ct = 0; ct < 4; ++ct)
#pragma unroll
      for (int dt = 0; dt < 2; ++dt)
        vf[ct * 2 + dt] = *reinterpret_cast<const f16x4*>(
            vp + (size_t)(dt * 16 + lr) * MP + m0 + ct * 16 + lg * 4);
    attn_tile<false>(kf, qf, vf, O, psum, lg, 0);
#pragma unroll
    for (int ct = 0; ct < 4; ++ct) kf[ct] = kn[ct];
  }
  {  // tail tile m0 = 2496 (4 valid m)
    const int m0 = NFULL * 64;
    bf16x8 kt[4];
#pragma unroll
    for (int ct = 0; ct < 4; ++ct) {
      const int mr = m0 + ct * 16 + lr;
      kt[ct] = (bf16x8){0, 0, 0, 0, 0, 0, 0, 0};
      if (mr < M) kt[ct] = *reinterpret_cast<const bf16x8*>(kp + (size_t)mr * DK + lg * 8);
    }
    f16x4 vf[8];
#pragma unroll
    for (int ct = 0; ct < 4; ++ct)
#pragma unroll
      for (int dt = 0; dt < 2; ++dt)
        vf[ct * 2 + dt] = *reinterpret_cast<const f16x4*>(
            vp + (size_t)(dt * 16 + lr) * MP + m0 + ct * 16 + lg * 4);
    attn_tile<true>(kt, qf, vf, O, psum, lg, M - m0);
  }

  // psum total for q-row lr lives in lanes {lr, lr+16, lr+32, lr+48}
  psum += __shfl_xor(psum, 16);
  psum += __shfl_xor(psum, 32);
  const float inv = 1.f / psum;
  float invq[4];
#pragma unroll
  for (int i = 0; i < 4; ++i) invq[i] = __shfl(inv, lg * 4 + i);
#pragma unroll
  for (int i = 0; i < 4; ++i) {
    const int rq = n0 + lg * 4 + i;
    if (rq >= N) continue;
    float* ob = out + ((size_t)b * N + rq) * C + h * DK + lr;
    ob[0] = O[0][i] * invq[i];
    ob[16] = O[1][i] * invq[i];
  }
}

// ---------------------------------------------------------------------------
extern "C" void kernel_launch(void* const* d_in, const int* in_sizes, int n_in,
                              void* d_out, int out_size, void* d_ws, size_t ws_size,
                              hipStream_t stream) {
  (void)in_sizes; (void)n_in; (void)out_size; (void)ws_size;
  const float* x     = (const float*)d_in[0];
  const float* Wq    = (const float*)d_in[1];
  const float* bq    = (const float*)d_in[2];
  const float* Wk    = (const float*)d_in[3];
  const float* bk    = (const float*)d_in[4];
  const float* Wv    = (const float*)d_in[5];
  const float* bv    = (const float*)d_in[6];
  const float* Wc    = (const float*)d_in[7];
  const float* bc    = (const float*)d_in[8];
  const float* gamma = (const float*)d_in[9];
  const float* beta  = (const float*)d_in[10];
  float* out = (float*)d_out;

  char* wsb = (char*)d_ws;
  // region0 (0..20.48MB): fp16 conv partials; dead after ln -> overlaid by qb/kb/vt
  ushort* xpart = (ushort*)wsb;
  ushort* qb = (ushort*)wsb;                       // 5,120,000 B
  ushort* kb = (ushort*)(wsb + 5120000);           // 2,560,000 B
  ushort* vt = (ushort*)(wsb + 7680000);           // 2,572,288 B (+4KB zero guard)
  char* p = wsb + 20480000;
  ushort* xTt  = (ushort*)p;                       // 5,144,576 B; dead after conv
  ushort* xr16 = (ushort*)p;                       // overlay (written at ln)
  p += 5144576;
  ushort* xb16 = (ushort*)p; p += 5120000;         // 5,120,000 B
  ushort* W16  = (ushort*)p;                       // 393,216 B
  // total = 31,137,792 B

  wcast<<<dim3(64, 3), 256, 0, stream>>>(Wq, Wk, Wv, W16);
  xt_cast<<<dim3((N + 63) / 64, C / 64, B), 256, 0, stream>>>(x, xTt, xb16);
  conv_mfma<<<dim3(MTILES * SPLIT), 256, 0, stream>>>(Wc, xTt, xpart);
  ln_kernel<<<dim3(B * M), 256, 0, stream>>>(xpart, bc, gamma, beta, xr16);
  // zero V^T (incl. pad + 4KB guard past the buffer for the tail-tile fragment overrun)
  (void)hipMemsetAsync(vt, 0, (size_t)B * H * DK * MP * 2 + 4096, stream);
  proj_all<<<dim3((B * N + 63) / 64, C / 64, 3), 256, 0, stream>>>(xb16, xr16, W16, bq, bk, bv,
                                                                   qb, kb, vt);
  attn5<<<dim3((N + 63) / 64, H, B), 256, 0, stream>>>(qb, kb, vt, out);
}

// Round 11
// 263.107 us; speedup vs baseline: 2.2410x; 2.2410x over previous
//
#include <hip/hip_runtime.h>
#include <hip/hip_bf16.h>
#include <hip/hip_fp16.h>
#include <math.h>

constexpr int B = 2;
constexpr int N = 5000;
constexpr int C = 256;
constexpr int H = 8;
constexpr int DK = 32;
constexpr int M = 2500;
constexpr int MP = 2512;            // padded V stride (16-elem multiple)
constexpr int KSTEPS = 157;         // ceil(5000/32)
constexpr int SPLIT = 8;            // conv split-K (== XCD count)
constexpr int MTILES = 79;          // ceil(2500/32)
constexpr float QSCALE = 0.2550598692503365f;        // (1/sqrt(32)) * log2(e)

typedef __attribute__((ext_vector_type(8))) short bf16x8;
typedef __attribute__((ext_vector_type(4))) float f32x4;
typedef __fp16 h16x2 __attribute__((ext_vector_type(2)));
typedef _Float16 f16x4 __attribute__((ext_vector_type(4)));

static __device__ __forceinline__ ushort f2bf(float f) {
  __hip_bfloat16 h = __float2bfloat16(f);
  return *reinterpret_cast<ushort*>(&h);
}

static __device__ __forceinline__ float fastexp2(float x) {
#if __has_builtin(__builtin_amdgcn_exp2f)
  return __builtin_amdgcn_exp2f(x);
#else
  return exp2f(x);
#endif
}

// ---------------------------------------------------------------------------
// K0a: cast Wq|Wk|Wv fp32 -> bf16 into W16[3][C][C]
// ---------------------------------------------------------------------------
__global__ __launch_bounds__(256) void wcast(const float* __restrict__ Wq,
                                             const float* __restrict__ Wk,
                                             const float* __restrict__ Wv,
                                             ushort* __restrict__ W16) {
  const float* src = (blockIdx.y == 0) ? Wq : (blockIdx.y == 1) ? Wk : Wv;
  const int idx = blockIdx.x * 1024 + threadIdx.x * 4;
  const float4 v = *reinterpret_cast<const float4*>(src + idx);
  ushort4 o;
  o.x = f2bf(v.x); o.y = f2bf(v.y); o.z = f2bf(v.z); o.w = f2bf(v.w);
  *reinterpret_cast<ushort4*>(W16 + (size_t)blockIdx.y * C * C + idx) = o;
}

// ---------------------------------------------------------------------------
// K0b: x fp32 -> xTt[b][ks][c][32] bf16 (k-step-blocked, zero pad) AND xb16[b][n][c]
// ---------------------------------------------------------------------------
__global__ __launch_bounds__(256) void xt_cast(const float* __restrict__ x,
                                               ushort* __restrict__ xTt,
                                               ushort* __restrict__ xb16) {
  const int n0 = blockIdx.x * 64, c0 = blockIdx.y * 64, b = blockIdx.z;
  const int tid = threadIdx.x;
  __shared__ ushort T[64][68];  // [n][c]
  const float* xb = x + (size_t)b * N * C;
#pragma unroll
  for (int i = 0; i < 4; ++i) {
    const int nl = (tid >> 4) + i * 16;
    const int cg = (tid & 15) * 4;
    float4 v = {0.f, 0.f, 0.f, 0.f};
    const bool ok = (n0 + nl) < N;
    if (ok) v = *reinterpret_cast<const float4*>(xb + (size_t)(n0 + nl) * C + c0 + cg);
    ushort4 u;
    u.x = f2bf(v.x); u.y = f2bf(v.y); u.z = f2bf(v.z); u.w = f2bf(v.w);
    T[nl][cg + 0] = u.x; T[nl][cg + 1] = u.y; T[nl][cg + 2] = u.z; T[nl][cg + 3] = u.w;
    if (ok)
      *reinterpret_cast<ushort4*>(xb16 + ((size_t)b * N + n0 + nl) * C + c0 + cg) = u;
  }
  __syncthreads();
  ushort* ob = xTt + (size_t)b * KSTEPS * C * 32;
  const int cl = tid & 63, ng = tid >> 6;
#pragma unroll
  for (int j = 0; j < 2; ++j) {
    const int nstart = ng * 16 + j * 8;   // 0,8,...,56
    const int n = n0 + nstart;
    if (n >= KSTEPS * 32) continue;
    const int ks = n >> 5, kk = n & 31;
    ushort vals[8];
#pragma unroll
    for (int jj = 0; jj < 8; ++jj) vals[jj] = T[nstart + jj][cl];
    *reinterpret_cast<bf16x8*>(ob + ((size_t)ks * C + (c0 + cl)) * 32 + kk) =
        *reinterpret_cast<const bf16x8*>(vals);
  }
}

// ---------------------------------------------------------------------------
// K1: conv via MFMA — coalesced direct-load, merged batch, XCD-affine split-K.
// ---------------------------------------------------------------------------
__global__ __launch_bounds__(256) void conv_mfma(const float* __restrict__ Wc,
                                                 const ushort* __restrict__ xTt,
                                                 ushort* __restrict__ xpart) {
  const int s = blockIdx.x & 7;
  const int mt = blockIdx.x >> 3;
  const int m0 = mt * 32;
  const int tid = threadIdx.x, w = tid >> 6, l = tid & 63;
  const int lr = l & 15, lg = l >> 4;
  f32x4 acc[16];
#pragma unroll
  for (int i = 0; i < 16; ++i) acc[i] = (f32x4){0.f, 0.f, 0.f, 0.f};
  const int row0 = m0 + lr, row1 = m0 + 16 + lr;
  const bool ok0 = row0 < M, ok1 = row1 < M;
  const float* ap0 = Wc + (size_t)(ok0 ? row0 : 0) * N + lg * 8;
  const float* ap1 = Wc + (size_t)(ok1 ? row1 : 0) * N + lg * 8;
  const int crow = w * 64 + lr;

#pragma unroll 2
  for (int ks = s; ks < KSTEPS; ks += SPLIT) {
    const int n0 = ks * 32;
    const bool kok = (n0 + lg * 8) < N;
    bf16x8 a0 = {0, 0, 0, 0, 0, 0, 0, 0}, a1 = {0, 0, 0, 0, 0, 0, 0, 0};
    if (ok0 && kok) {
      const float4 v0 = *reinterpret_cast<const float4*>(ap0 + n0);
      const float4 v1 = *reinterpret_cast<const float4*>(ap0 + n0 + 4);
      ushort u[8];
      u[0] = f2bf(v0.x); u[1] = f2bf(v0.y); u[2] = f2bf(v0.z); u[3] = f2bf(v0.w);
      u[4] = f2bf(v1.x); u[5] = f2bf(v1.y); u[6] = f2bf(v1.z); u[7] = f2bf(v1.w);
      a0 = *reinterpret_cast<const bf16x8*>(u);
    }
    if (ok1 && kok) {
      const float4 v0 = *reinterpret_cast<const float4*>(ap1 + n0);
      const float4 v1 = *reinterpret_cast<const float4*>(ap1 + n0 + 4);
      ushort u[8];
      u[0] = f2bf(v0.x); u[1] = f2bf(v0.y); u[2] = f2bf(v0.z); u[3] = f2bf(v0.w);
      u[4] = f2bf(v1.x); u[5] = f2bf(v1.y); u[6] = f2bf(v1.z); u[7] = f2bf(v1.w);
      a1 = *reinterpret_cast<const bf16x8*>(u);
    }
    bf16x8 bf[8];
#pragma unroll
    for (int ct = 0; ct < 4; ++ct)
#pragma unroll
      for (int bb = 0; bb < 2; ++bb)
        bf[ct * 2 + bb] = *reinterpret_cast<const bf16x8*>(
            xTt + (((size_t)bb * KSTEPS + ks) * C + crow + ct * 16) * 32 + lg * 8);
#pragma unroll
    for (int ct = 0; ct < 4; ++ct)
#pragma unroll
      for (int bb = 0; bb < 2; ++bb) {
        acc[(0 * 4 + ct) * 2 + bb] =
            __builtin_amdgcn_mfma_f32_16x16x32_bf16(a0, bf[ct * 2 + bb], acc[(0 * 4 + ct) * 2 + bb], 0, 0, 0);
        acc[(1 * 4 + ct) * 2 + bb] =
            __builtin_amdgcn_mfma_f32_16x16x32_bf16(a1, bf[ct * 2 + bb], acc[(1 * 4 + ct) * 2 + bb], 0, 0, 0);
      }
  }

#pragma unroll
  for (int mf = 0; mf < 2; ++mf)
#pragma unroll
    for (int ct = 0; ct < 4; ++ct)
#pragma unroll
      for (int bb = 0; bb < 2; ++bb)
#pragma unroll
        for (int i = 0; i < 4; ++i) {
          const int m = m0 + mf * 16 + lg * 4 + i;
          if (m < M) {
            const __half hv = __float2half(acc[(mf * 4 + ct) * 2 + bb][i]);
            xpart[(((size_t)s * B + bb) * M + m) * C + w * 64 + ct * 16 + lr] =
                *reinterpret_cast<const ushort*>(&hv);
          }
        }
}

// ---------------------------------------------------------------------------
// K2: sum SPLIT fp16 partials + bc + LayerNorm -> bf16 row-major xr16
// ---------------------------------------------------------------------------
__global__ __launch_bounds__(256) void ln_kernel(const ushort* __restrict__ xp,
                                                 const float* __restrict__ bc,
                                                 const float* __restrict__ gamma,
                                                 const float* __restrict__ beta,
                                                 ushort* __restrict__ xr16) {
  const int row = blockIdx.x;  // b*M + m
  const int tid = threadIdx.x;
  const int b = row / M, m = row - b * M;
  const size_t base = (size_t)row * C;
  float v = bc[m];
#pragma unroll
  for (int s = 0; s < SPLIT; ++s) {
    const ushort us = xp[(((size_t)s * B + b) * M + m) * C + tid];
    v += __half2float(*reinterpret_cast<const __half*>(&us));
  }
  __shared__ float red[8];
  float sum = v;
#pragma unroll
  for (int o = 32; o >= 1; o >>= 1) sum += __shfl_xor(sum, o);
  if ((tid & 63) == 0) red[tid >> 6] = sum;
  __syncthreads();
  const float mu = (red[0] + red[1] + red[2] + red[3]) * (1.f / C);
  const float d = v - mu;
  float s2 = d * d;
#pragma unroll
  for (int o = 32; o >= 1; o >>= 1) s2 += __shfl_xor(s2, o);
  if ((tid & 63) == 0) red[4 + (tid >> 6)] = s2;
  __syncthreads();
  const float var = (red[4] + red[5] + red[6] + red[7]) * (1.f / C);
  xr16[base + tid] = f2bf(gamma[tid] * d * rsqrtf(var + 1e-5f) + beta[tid]);
}

// ---------------------------------------------------------------------------
// K3: projections via MFMA. grid.z: 0=Q(xb16, scale=QSCALE incl log2e), 1=K(xr16),
// 2=V^T(xr16, stored FP16 d-major stride MP — feeds PV's 16x16x16 f16 MFMA).
// ---------------------------------------------------------------------------
__global__ __launch_bounds__(256) void proj_all(const ushort* __restrict__ xb16,
                                                const ushort* __restrict__ xr16,
                                                const ushort* __restrict__ W16,
                                                const float* __restrict__ bq,
                                                const float* __restrict__ bk,
                                                const float* __restrict__ bv,
                                                ushort* __restrict__ qb,
                                                ushort* __restrict__ kb,
                                                ushort* __restrict__ vt) {
  const int z = blockIdx.z;
  const int R = (z == 0) ? N : M;
  const int totalRows = B * R;
  if (blockIdx.x * 64 >= totalRows) return;
  const ushort* xin = (z == 0) ? xb16 : xr16;
  const ushort* W = W16 + (size_t)z * C * C;
  const float* bias = (z == 0) ? bq : (z == 1) ? bk : bv;
  const int tid = threadIdx.x, w = tid >> 6, l = tid & 63;
  const int lr = l & 15, lg = l >> 4;
  const int r0 = blockIdx.x * 64 + w * 16;
  const int c0 = blockIdx.y * 64;
  const int arow = r0 + lr;
  const bool aok = arow < totalRows;
  f32x4 acc[4] = {{0.f,0.f,0.f,0.f},{0.f,0.f,0.f,0.f},{0.f,0.f,0.f,0.f},{0.f,0.f,0.f,0.f}};
#pragma unroll
  for (int ks = 0; ks < 8; ++ks) {
    bf16x8 af = {0, 0, 0, 0, 0, 0, 0, 0};
    if (aok) af = *reinterpret_cast<const bf16x8*>(xin + (size_t)arow * C + ks * 32 + lg * 8);
#pragma unroll
    for (int ct = 0; ct < 4; ++ct) {
      const bf16x8 bf =
          *reinterpret_cast<const bf16x8*>(W + (size_t)(c0 + ct * 16 + lr) * C + ks * 32 + lg * 8);
      acc[ct] = __builtin_amdgcn_mfma_f32_16x16x32_bf16(af, bf, acc[ct], 0, 0, 0);
    }
  }
#pragma unroll
  for (int ct = 0; ct < 4; ++ct) {
    const int c = c0 + ct * 16 + lr;
    const int h = c >> 5, d = c & 31;
    const float bi = bias[c];
#pragma unroll
    for (int i = 0; i < 4; ++i) {
      const int row = r0 + lg * 4 + i;
      if (row >= totalRows) continue;
      const int bb = (row >= R) ? 1 : 0;
      const int rr = row - bb * R;
      float val = acc[ct][i] + bi;
      if (z == 0) {
        val *= QSCALE;
        qb[(((size_t)bb * H + h) * N + rr) * DK + d] = f2bf(val);
      } else if (z == 1) {
        kb[(((size_t)bb * H + h) * M + rr) * DK + d] = f2bf(val);
      } else {
        const __half hv = __float2half(val);
        vt[(((size_t)bb * H + h) * DK + d) * MP + rr] = *reinterpret_cast<const ushort*>(&hv);
      }
    }
  }
}

// ---------------------------------------------------------------------------
// K4: register-chained flash attention (R10 math, register-budgeted).
// Swapped QK^T D-layout == 16x16x16f16 A-layout, so exp2 output feeds PV
// directly — no LDS/shuffles. Explicit 1-stage K/V double buffer; unroll 1;
// __launch_bounds__(256,4) = 128-VGPR budget so prefetch stays hoisted.
// ---------------------------------------------------------------------------
static __device__ __forceinline__ void load_kv(const ushort* __restrict__ kp,
                                               const _Float16* __restrict__ vp,
                                               int m0, int lr, int lg,
                                               bf16x8 (&kf)[4], f16x4 (&vf)[8]) {
#pragma unroll
  for (int ct = 0; ct < 4; ++ct)
    kf[ct] = *reinterpret_cast<const bf16x8*>(kp + (size_t)(m0 + ct * 16 + lr) * DK + lg * 8);
#pragma unroll
  for (int ct = 0; ct < 4; ++ct)
#pragma unroll
    for (int dt = 0; dt < 2; ++dt)
      vf[ct * 2 + dt] = *reinterpret_cast<const f16x4*>(
          vp + (size_t)(dt * 16 + lr) * MP + m0 + ct * 16 + lg * 4);
}

template <bool TAIL>
static __device__ __forceinline__ void attn_tile(const bf16x8 (&kf)[4], const bf16x8& qf,
                                                 const f16x4 (&vf)[8], f32x4 (&O)[2],
                                                 float& psum, int lg, int mlim) {
  f32x4 s[4];
#pragma unroll
  for (int ct = 0; ct < 4; ++ct)
    s[ct] = __builtin_amdgcn_mfma_f32_16x16x32_bf16(kf[ct], qf, (f32x4){0.f, 0.f, 0.f, 0.f}, 0, 0, 0);
#pragma unroll
  for (int ct = 0; ct < 4; ++ct) {
    float pv[4];
#pragma unroll
    for (int i = 0; i < 4; ++i) {
      float e = fastexp2(s[ct][i]);
      if (TAIL) {
        if (ct * 16 + lg * 4 + i >= mlim) e = 0.f;
      }
      pv[i] = e;
      psum += e;
    }
    union {
      h16x2 h2[2];
      f16x4 v;
    } pk;
    pk.h2[0] = __builtin_amdgcn_cvt_pkrtz(pv[0], pv[1]);
    pk.h2[1] = __builtin_amdgcn_cvt_pkrtz(pv[2], pv[3]);
    const f16x4 pa = pk.v;
#pragma unroll
    for (int dt = 0; dt < 2; ++dt)
      O[dt] = __builtin_amdgcn_mfma_f32_16x16x16f16(pa, vf[ct * 2 + dt], O[dt], 0, 0, 0);
  }
}

__global__ __launch_bounds__(256, 4) void attn6(const ushort* __restrict__ q,
                                                const ushort* __restrict__ kk,
                                                const ushort* __restrict__ vt,
                                                float* __restrict__ out) {
  const int qt = blockIdx.x, h = blockIdx.y, b = blockIdx.z;
  const int tid = threadIdx.x, w = tid >> 6, l = tid & 63;
  const int lr = l & 15, lg = l >> 4;
  const int n0 = qt * 64 + w * 16;
  const ushort* qp = q + (size_t)(b * H + h) * N * DK;
  const ushort* kp = kk + (size_t)(b * H + h) * M * DK;
  const _Float16* vp = (const _Float16*)vt + (size_t)(b * H + h) * DK * MP;

  bf16x8 qf = {0, 0, 0, 0, 0, 0, 0, 0};
  if (n0 + lr < N) qf = *reinterpret_cast<const bf16x8*>(qp + (size_t)(n0 + lr) * DK + lg * 8);

  f32x4 O[2] = {{0.f, 0.f, 0.f, 0.f}, {0.f, 0.f, 0.f, 0.f}};
  float psum = 0.f;

  constexpr int NFULL = M / 64;  // 39
  bf16x8 kA[4];
  f16x4 vA[8];
  load_kv(kp, vp, 0, lr, lg, kA, vA);

#pragma unroll 1
  for (int t = 0; t < NFULL; ++t) {
    // issue next stage's loads before computing current (1-stage pipeline)
    const int tn = (t + 1 < NFULL) ? t + 1 : t;
    bf16x8 kB[4];
    f16x4 vB[8];
    load_kv(kp, vp, tn * 64, lr, lg, kB, vB);
    attn_tile<false>(kA, qf, vA, O, psum, lg, 0);
#pragma unroll
    for (int ct = 0; ct < 4; ++ct) kA[ct] = kB[ct];
#pragma unroll
    for (int i = 0; i < 8; ++i) vA[i] = vB[i];
  }
  {  // tail tile m0 = 2496 (4 valid m)
    const int m0 = NFULL * 64;
    bf16x8 kt[4];
#pragma unroll
    for (int ct = 0; ct < 4; ++ct) {
      const int mr = m0 + ct * 16 + lr;
      kt[ct] = (bf16x8){0, 0, 0, 0, 0, 0, 0, 0};
      if (mr < M) kt[ct] = *reinterpret_cast<const bf16x8*>(kp + (size_t)mr * DK + lg * 8);
    }
    f16x4 vf[8];
#pragma unroll
    for (int ct = 0; ct < 4; ++ct)
#pragma unroll
      for (int dt = 0; dt < 2; ++dt)
        vf[ct * 2 + dt] = *reinterpret_cast<const f16x4*>(
            vp + (size_t)(dt * 16 + lr) * MP + m0 + ct * 16 + lg * 4);
    attn_tile<true>(kt, qf, vf, O, psum, lg, M - m0);
  }

  // psum total for q-row lr lives in lanes {lr, lr+16, lr+32, lr+48}
  psum += __shfl_xor(psum, 16);
  psum += __shfl_xor(psum, 32);
  const float inv = 1.f / psum;
  float invq[4];
#pragma unroll
  for (int i = 0; i < 4; ++i) invq[i] = __shfl(inv, lg * 4 + i);
#pragma unroll
  for (int i = 0; i < 4; ++i) {
    const int rq = n0 + lg * 4 + i;
    if (rq >= N) continue;
    float* ob = out + ((size_t)b * N + rq) * C + h * DK + lr;
    ob[0] = O[0][i] * invq[i];
    ob[16] = O[1][i] * invq[i];
  }
}

// ---------------------------------------------------------------------------
extern "C" void kernel_launch(void* const* d_in, const int* in_sizes, int n_in,
                              void* d_out, int out_size, void* d_ws, size_t ws_size,
                              hipStream_t stream) {
  (void)in_sizes; (void)n_in; (void)out_size; (void)ws_size;
  const float* x     = (const float*)d_in[0];
  const float* Wq    = (const float*)d_in[1];
  const float* bq    = (const float*)d_in[2];
  const float* Wk    = (const float*)d_in[3];
  const float* bk    = (const float*)d_in[4];
  const float* Wv    = (const float*)d_in[5];
  const float* bv    = (const float*)d_in[6];
  const float* Wc    = (const float*)d_in[7];
  const float* bc    = (const float*)d_in[8];
  const float* gamma = (const float*)d_in[9];
  const float* beta  = (const float*)d_in[10];
  float* out = (float*)d_out;

  char* wsb = (char*)d_ws;
  // region0 (0..20.48MB): fp16 conv partials; dead after ln -> overlaid by qb/kb/vt
  ushort* xpart = (ushort*)wsb;
  ushort* qb = (ushort*)wsb;                       // 5,120,000 B
  ushort* kb = (ushort*)(wsb + 5120000);           // 2,560,000 B
  ushort* vt = (ushort*)(wsb + 7680000);           // 2,572,288 B (+4KB zero guard)
  char* p = wsb + 20480000;
  ushort* xTt  = (ushort*)p;                       // 5,144,576 B; dead after conv
  ushort* xr16 = (ushort*)p;                       // overlay (written at ln)
  p += 5144576;
  ushort* xb16 = (ushort*)p; p += 5120000;         // 5,120,000 B
  ushort* W16  = (ushort*)p;                       // 393,216 B
  // total = 31,137,792 B

  wcast<<<dim3(64, 3), 256, 0, stream>>>(Wq, Wk, Wv, W16);
  xt_cast<<<dim3((N + 63) / 64, C / 64, B), 256, 0, stream>>>(x, xTt, xb16);
  conv_mfma<<<dim3(MTILES * SPLIT), 256, 0, stream>>>(Wc, xTt, xpart);
  ln_kernel<<<dim3(B * M), 256, 0, stream>>>(xpart, bc, gamma, beta, xr16);
  // zero V^T (incl. pad + 4KB guard past the buffer for the tail-tile fragment overrun)
  (void)hipMemsetAsync(vt, 0, (size_t)B * H * DK * MP * 2 + 4096, stream);
  proj_all<<<dim3((B * N + 63) / 64, C / 64, 3), 256, 0, stream>>>(xb16, xr16, W16, bq, bk, bv,
                                                                   qb, kb, vt);
  attn6<<<dim3((N + 63) / 64, H, B), 256, 0, stream>>>(qb, kb, vt, out);
}

// Round 12
// 254.303 us; speedup vs baseline: 2.3186x; 1.0346x over previous
//
#include <hip/hip_runtime.h>
#include <hip/hip_bf16.h>
#include <hip/hip_fp16.h>
#include <math.h>

constexpr int B = 2;
constexpr int N = 5000;
constexpr int C = 256;
constexpr int H = 8;
constexpr int DK = 32;
constexpr int M = 2500;
constexpr int MP = 2512;            // padded V stride (16-elem multiple)
constexpr int KSTEPS = 157;         // ceil(5000/32)
constexpr int SPLIT = 8;            // conv split-K (== XCD count)
constexpr int MTILES = 79;          // ceil(2500/32)
constexpr float QSCALE = 0.2550598692503365f;        // (1/sqrt(32)) * log2(e)

typedef __attribute__((ext_vector_type(8))) short bf16x8;
typedef __attribute__((ext_vector_type(4))) float f32x4;
typedef __fp16 h16x2 __attribute__((ext_vector_type(2)));
typedef _Float16 f16x4 __attribute__((ext_vector_type(4)));

static __device__ __forceinline__ ushort f2bf(float f) {
  __hip_bfloat16 h = __float2bfloat16(f);
  return *reinterpret_cast<ushort*>(&h);
}

static __device__ __forceinline__ float fastexp2(float x) {
#if __has_builtin(__builtin_amdgcn_exp2f)
  return __builtin_amdgcn_exp2f(x);
#else
  return exp2f(x);
#endif
}

// ---------------------------------------------------------------------------
// K0a: cast Wq|Wk|Wv fp32 -> bf16 into W16[3][C][C]
// ---------------------------------------------------------------------------
__global__ __launch_bounds__(256) void wcast(const float* __restrict__ Wq,
                                             const float* __restrict__ Wk,
                                             const float* __restrict__ Wv,
                                             ushort* __restrict__ W16) {
  const float* src = (blockIdx.y == 0) ? Wq : (blockIdx.y == 1) ? Wk : Wv;
  const int idx = blockIdx.x * 1024 + threadIdx.x * 4;
  const float4 v = *reinterpret_cast<const float4*>(src + idx);
  ushort4 o;
  o.x = f2bf(v.x); o.y = f2bf(v.y); o.z = f2bf(v.z); o.w = f2bf(v.w);
  *reinterpret_cast<ushort4*>(W16 + (size_t)blockIdx.y * C * C + idx) = o;
}

// ---------------------------------------------------------------------------
// K0b: x fp32 -> xTt[b][ks][c][32] bf16 (k-step-blocked, zero pad) AND xb16[b][n][c]
// ---------------------------------------------------------------------------
__global__ __launch_bounds__(256) void xt_cast(const float* __restrict__ x,
                                               ushort* __restrict__ xTt,
                                               ushort* __restrict__ xb16) {
  const int n0 = blockIdx.x * 64, c0 = blockIdx.y * 64, b = blockIdx.z;
  const int tid = threadIdx.x;
  __shared__ ushort T[64][68];  // [n][c]
  const float* xb = x + (size_t)b * N * C;
#pragma unroll
  for (int i = 0; i < 4; ++i) {
    const int nl = (tid >> 4) + i * 16;
    const int cg = (tid & 15) * 4;
    float4 v = {0.f, 0.f, 0.f, 0.f};
    const bool ok = (n0 + nl) < N;
    if (ok) v = *reinterpret_cast<const float4*>(xb + (size_t)(n0 + nl) * C + c0 + cg);
    ushort4 u;
    u.x = f2bf(v.x); u.y = f2bf(v.y); u.z = f2bf(v.z); u.w = f2bf(v.w);
    T[nl][cg + 0] = u.x; T[nl][cg + 1] = u.y; T[nl][cg + 2] = u.z; T[nl][cg + 3] = u.w;
    if (ok)
      *reinterpret_cast<ushort4*>(xb16 + ((size_t)b * N + n0 + nl) * C + c0 + cg) = u;
  }
  __syncthreads();
  ushort* ob = xTt + (size_t)b * KSTEPS * C * 32;
  const int cl = tid & 63, ng = tid >> 6;
#pragma unroll
  for (int j = 0; j < 2; ++j) {
    const int nstart = ng * 16 + j * 8;   // 0,8,...,56
    const int n = n0 + nstart;
    if (n >= KSTEPS * 32) continue;
    const int ks = n >> 5, kk = n & 31;
    ushort vals[8];
#pragma unroll
    for (int jj = 0; jj < 8; ++jj) vals[jj] = T[nstart + jj][cl];
    *reinterpret_cast<bf16x8*>(ob + ((size_t)ks * C + (c0 + cl)) * 32 + kk) =
        *reinterpret_cast<const bf16x8*>(vals);
  }
}

// ---------------------------------------------------------------------------
// K1: conv via MFMA — coalesced direct-load, merged batch, XCD-affine split-K.
// ---------------------------------------------------------------------------
__global__ __launch_bounds__(256) void conv_mfma(const float* __restrict__ Wc,
                                                 const ushort* __restrict__ xTt,
                                                 ushort* __restrict__ xpart) {
  const int s = blockIdx.x & 7;
  const int mt = blockIdx.x >> 3;
  const int m0 = mt * 32;
  const int tid = threadIdx.x, w = tid >> 6, l = tid & 63;
  const int lr = l & 15, lg = l >> 4;
  f32x4 acc[16];
#pragma unroll
  for (int i = 0; i < 16; ++i) acc[i] = (f32x4){0.f, 0.f, 0.f, 0.f};
  const int row0 = m0 + lr, row1 = m0 + 16 + lr;
  const bool ok0 = row0 < M, ok1 = row1 < M;
  const float* ap0 = Wc + (size_t)(ok0 ? row0 : 0) * N + lg * 8;
  const float* ap1 = Wc + (size_t)(ok1 ? row1 : 0) * N + lg * 8;
  const int crow = w * 64 + lr;

#pragma unroll 2
  for (int ks = s; ks < KSTEPS; ks += SPLIT) {
    const int n0 = ks * 32;
    const bool kok = (n0 + lg * 8) < N;
    bf16x8 a0 = {0, 0, 0, 0, 0, 0, 0, 0}, a1 = {0, 0, 0, 0, 0, 0, 0, 0};
    if (ok0 && kok) {
      const float4 v0 = *reinterpret_cast<const float4*>(ap0 + n0);
      const float4 v1 = *reinterpret_cast<const float4*>(ap0 + n0 + 4);
      ushort u[8];
      u[0] = f2bf(v0.x); u[1] = f2bf(v0.y); u[2] = f2bf(v0.z); u[3] = f2bf(v0.w);
      u[4] = f2bf(v1.x); u[5] = f2bf(v1.y); u[6] = f2bf(v1.z); u[7] = f2bf(v1.w);
      a0 = *reinterpret_cast<const bf16x8*>(u);
    }
    if (ok1 && kok) {
      const float4 v0 = *reinterpret_cast<const float4*>(ap1 + n0);
      const float4 v1 = *reinterpret_cast<const float4*>(ap1 + n0 + 4);
      ushort u[8];
      u[0] = f2bf(v0.x); u[1] = f2bf(v0.y); u[2] = f2bf(v0.z); u[3] = f2bf(v0.w);
      u[4] = f2bf(v1.x); u[5] = f2bf(v1.y); u[6] = f2bf(v1.z); u[7] = f2bf(v1.w);
      a1 = *reinterpret_cast<const bf16x8*>(u);
    }
    bf16x8 bf[8];
#pragma unroll
    for (int ct = 0; ct < 4; ++ct)
#pragma unroll
      for (int bb = 0; bb < 2; ++bb)
        bf[ct * 2 + bb] = *reinterpret_cast<const bf16x8*>(
            xTt + (((size_t)bb * KSTEPS + ks) * C + crow + ct * 16) * 32 + lg * 8);
#pragma unroll
    for (int ct = 0; ct < 4; ++ct)
#pragma unroll
      for (int bb = 0; bb < 2; ++bb) {
        acc[(0 * 4 + ct) * 2 + bb] =
            __builtin_amdgcn_mfma_f32_16x16x32_bf16(a0, bf[ct * 2 + bb], acc[(0 * 4 + ct) * 2 + bb], 0, 0, 0);
        acc[(1 * 4 + ct) * 2 + bb] =
            __builtin_amdgcn_mfma_f32_16x16x32_bf16(a1, bf[ct * 2 + bb], acc[(1 * 4 + ct) * 2 + bb], 0, 0, 0);
      }
  }

#pragma unroll
  for (int mf = 0; mf < 2; ++mf)
#pragma unroll
    for (int ct = 0; ct < 4; ++ct)
#pragma unroll
      for (int bb = 0; bb < 2; ++bb)
#pragma unroll
        for (int i = 0; i < 4; ++i) {
          const int m = m0 + mf * 16 + lg * 4 + i;
          if (m < M) {
            const __half hv = __float2half(acc[(mf * 4 + ct) * 2 + bb][i]);
            xpart[(((size_t)s * B + bb) * M + m) * C + w * 64 + ct * 16 + lr] =
                *reinterpret_cast<const ushort*>(&hv);
          }
        }
}

// ---------------------------------------------------------------------------
// K2: sum SPLIT fp16 partials + bc + LayerNorm -> bf16 row-major xr16
// ---------------------------------------------------------------------------
__global__ __launch_bounds__(256) void ln_kernel(const ushort* __restrict__ xp,
                                                 const float* __restrict__ bc,
                                                 const float* __restrict__ gamma,
                                                 const float* __restrict__ beta,
                                                 ushort* __restrict__ xr16) {
  const int row = blockIdx.x;  // b*M + m
  const int tid = threadIdx.x;
  const int b = row / M, m = row - b * M;
  const size_t base = (size_t)row * C;
  float v = bc[m];
#pragma unroll
  for (int s = 0; s < SPLIT; ++s) {
    const ushort us = xp[(((size_t)s * B + b) * M + m) * C + tid];
    v += __half2float(*reinterpret_cast<const __half*>(&us));
  }
  __shared__ float red[8];
  float sum = v;
#pragma unroll
  for (int o = 32; o >= 1; o >>= 1) sum += __shfl_xor(sum, o);
  if ((tid & 63) == 0) red[tid >> 6] = sum;
  __syncthreads();
  const float mu = (red[0] + red[1] + red[2] + red[3]) * (1.f / C);
  const float d = v - mu;
  float s2 = d * d;
#pragma unroll
  for (int o = 32; o >= 1; o >>= 1) s2 += __shfl_xor(s2, o);
  if ((tid & 63) == 0) red[4 + (tid >> 6)] = s2;
  __syncthreads();
  const float var = (red[4] + red[5] + red[6] + red[7]) * (1.f / C);
  xr16[base + tid] = f2bf(gamma[tid] * d * rsqrtf(var + 1e-5f) + beta[tid]);
}

// ---------------------------------------------------------------------------
// K3: projections via MFMA. grid.z: 0=Q(xb16, scale=QSCALE incl log2e), 1=K(xr16),
// 2=V^T(xr16, stored FP16 d-major stride MP — feeds PV's 16x16x16 f16 MFMA).
// ---------------------------------------------------------------------------
__global__ __launch_bounds__(256) void proj_all(const ushort* __restrict__ xb16,
                                                const ushort* __restrict__ xr16,
                                                const ushort* __restrict__ W16,
                                                const float* __restrict__ bq,
                                                const float* __restrict__ bk,
                                                const float* __restrict__ bv,
                                                ushort* __restrict__ qb,
                                                ushort* __restrict__ kb,
                                                ushort* __restrict__ vt) {
  const int z = blockIdx.z;
  const int R = (z == 0) ? N : M;
  const int totalRows = B * R;
  if (blockIdx.x * 64 >= totalRows) return;
  const ushort* xin = (z == 0) ? xb16 : xr16;
  const ushort* W = W16 + (size_t)z * C * C;
  const float* bias = (z == 0) ? bq : (z == 1) ? bk : bv;
  const int tid = threadIdx.x, w = tid >> 6, l = tid & 63;
  const int lr = l & 15, lg = l >> 4;
  const int r0 = blockIdx.x * 64 + w * 16;
  const int c0 = blockIdx.y * 64;
  const int arow = r0 + lr;
  const bool aok = arow < totalRows;
  f32x4 acc[4] = {{0.f,0.f,0.f,0.f},{0.f,0.f,0.f,0.f},{0.f,0.f,0.f,0.f},{0.f,0.f,0.f,0.f}};
#pragma unroll
  for (int ks = 0; ks < 8; ++ks) {
    bf16x8 af = {0, 0, 0, 0, 0, 0, 0, 0};
    if (aok) af = *reinterpret_cast<const bf16x8*>(xin + (size_t)arow * C + ks * 32 + lg * 8);
#pragma unroll
    for (int ct = 0; ct < 4; ++ct) {
      const bf16x8 bf =
          *reinterpret_cast<const bf16x8*>(W + (size_t)(c0 + ct * 16 + lr) * C + ks * 32 + lg * 8);
      acc[ct] = __builtin_amdgcn_mfma_f32_16x16x32_bf16(af, bf, acc[ct], 0, 0, 0);
    }
  }
#pragma unroll
  for (int ct = 0; ct < 4; ++ct) {
    const int c = c0 + ct * 16 + lr;
    const int h = c >> 5, d = c & 31;
    const float bi = bias[c];
#pragma unroll
    for (int i = 0; i < 4; ++i) {
      const int row = r0 + lg * 4 + i;
      if (row >= totalRows) continue;
      const int bb = (row >= R) ? 1 : 0;
      const int rr = row - bb * R;
      float val = acc[ct][i] + bi;
      if (z == 0) {
        val *= QSCALE;
        qb[(((size_t)bb * H + h) * N + rr) * DK + d] = f2bf(val);
      } else if (z == 1) {
        kb[(((size_t)bb * H + h) * M + rr) * DK + d] = f2bf(val);
      } else {
        const __half hv = __float2half(val);
        vt[(((size_t)bb * H + h) * DK + d) * MP + rr] = *reinterpret_cast<const ushort*>(&hv);
      }
    }
  }
}

// ---------------------------------------------------------------------------
// K4: register-chained flash attention with IN-BODY DUAL-CHAIN ILP.
// Each iteration processes two independent KV tiles (i and 20+i) with separate
// accumulators: loads and uses live in the same loop body, so the compiler
// cannot sink them across iterations; chain-B loads hide under chain-A compute.
// Swapped QK^T D-layout == 16x16x16f16 A-layout: exp2 feeds PV directly.
// ---------------------------------------------------------------------------
static __device__ __forceinline__ void load_kv(const ushort* __restrict__ kp,
                                               const _Float16* __restrict__ vp,
                                               int m0, int lr, int lg,
                                               bf16x8 (&kf)[4], f16x4 (&vf)[8]) {
#pragma unroll
  for (int ct = 0; ct < 4; ++ct)
    kf[ct] = *reinterpret_cast<const bf16x8*>(kp + (size_t)(m0 + ct * 16 + lr) * DK + lg * 8);
#pragma unroll
  for (int ct = 0; ct < 4; ++ct)
#pragma unroll
    for (int dt = 0; dt < 2; ++dt)
      vf[ct * 2 + dt] = *reinterpret_cast<const f16x4*>(
          vp + (size_t)(dt * 16 + lr) * MP + m0 + ct * 16 + lg * 4);
}

template <bool TAIL>
static __device__ __forceinline__ void attn_tile(const bf16x8 (&kf)[4], const bf16x8& qf,
                                                 const f16x4 (&vf)[8], f32x4 (&O)[2],
                                                 float& psum, int lg, int mlim) {
  f32x4 s[4];
#pragma unroll
  for (int ct = 0; ct < 4; ++ct)
    s[ct] = __builtin_amdgcn_mfma_f32_16x16x32_bf16(kf[ct], qf, (f32x4){0.f, 0.f, 0.f, 0.f}, 0, 0, 0);
#pragma unroll
  for (int ct = 0; ct < 4; ++ct) {
    float pv[4];
#pragma unroll
    for (int i = 0; i < 4; ++i) {
      float e = fastexp2(s[ct][i]);
      if (TAIL) {
        if (ct * 16 + lg * 4 + i >= mlim) e = 0.f;
      }
      pv[i] = e;
      psum += e;
    }
    union {
      h16x2 h2[2];
      f16x4 v;
    } pk;
    pk.h2[0] = __builtin_amdgcn_cvt_pkrtz(pv[0], pv[1]);
    pk.h2[1] = __builtin_amdgcn_cvt_pkrtz(pv[2], pv[3]);
    const f16x4 pa = pk.v;
#pragma unroll
    for (int dt = 0; dt < 2; ++dt)
      O[dt] = __builtin_amdgcn_mfma_f32_16x16x16f16(pa, vf[ct * 2 + dt], O[dt], 0, 0, 0);
  }
}

__global__ __launch_bounds__(256) void attn7(const ushort* __restrict__ q,
                                             const ushort* __restrict__ kk,
                                             const ushort* __restrict__ vt,
                                             float* __restrict__ out) {
  const int qt = blockIdx.x, h = blockIdx.y, b = blockIdx.z;
  const int tid = threadIdx.x, w = tid >> 6, l = tid & 63;
  const int lr = l & 15, lg = l >> 4;
  const int n0 = qt * 64 + w * 16;
  const ushort* qp = q + (size_t)(b * H + h) * N * DK;
  const ushort* kp = kk + (size_t)(b * H + h) * M * DK;
  const _Float16* vp = (const _Float16*)vt + (size_t)(b * H + h) * DK * MP;

  bf16x8 qf = {0, 0, 0, 0, 0, 0, 0, 0};
  if (n0 + lr < N) qf = *reinterpret_cast<const bf16x8*>(qp + (size_t)(n0 + lr) * DK + lg * 8);

  f32x4 Oa[2] = {{0.f, 0.f, 0.f, 0.f}, {0.f, 0.f, 0.f, 0.f}};
  f32x4 Ob[2] = {{0.f, 0.f, 0.f, 0.f}, {0.f, 0.f, 0.f, 0.f}};
  float psa = 0.f, psb = 0.f;

  // chain A: tiles 0..19 (20 full). chain B: tiles 20..38 full + tail (tile 39).
#pragma unroll 1
  for (int i = 0; i < 19; ++i) {
    const int ma = i * 64, mb = (20 + i) * 64;
    bf16x8 ka[4], kb_[4];
    f16x4 va[8], vb_[8];
    load_kv(kp, vp, ma, lr, lg, ka, va);
    load_kv(kp, vp, mb, lr, lg, kb_, vb_);
    attn_tile<false>(ka, qf, va, Oa, psa, lg, 0);
    attn_tile<false>(kb_, qf, vb_, Ob, psb, lg, 0);
  }
  {  // A tile 19 (full)
    bf16x8 ka[4];
    f16x4 va[8];
    load_kv(kp, vp, 19 * 64, lr, lg, ka, va);
    attn_tile<false>(ka, qf, va, Oa, psa, lg, 0);
  }
  {  // B tail tile 39: m0 = 2496, 4 valid m
    const int m0 = 39 * 64;
    bf16x8 kt[4];
#pragma unroll
    for (int ct = 0; ct < 4; ++ct) {
      const int mr = m0 + ct * 16 + lr;
      kt[ct] = (bf16x8){0, 0, 0, 0, 0, 0, 0, 0};
      if (mr < M) kt[ct] = *reinterpret_cast<const bf16x8*>(kp + (size_t)mr * DK + lg * 8);
    }
    f16x4 vf[8];
#pragma unroll
    for (int ct = 0; ct < 4; ++ct)
#pragma unroll
      for (int dt = 0; dt < 2; ++dt)
        vf[ct * 2 + dt] = *reinterpret_cast<const f16x4*>(
            vp + (size_t)(dt * 16 + lr) * MP + m0 + ct * 16 + lg * 4);
    attn_tile<true>(kt, qf, vf, Ob, psb, lg, M - m0);
  }

  // merge chains
  float psum = psa + psb;
  psum += __shfl_xor(psum, 16);
  psum += __shfl_xor(psum, 32);
  const float inv = 1.f / psum;
  float invq[4];
#pragma unroll
  for (int i = 0; i < 4; ++i) invq[i] = __shfl(inv, lg * 4 + i);
#pragma unroll
  for (int i = 0; i < 4; ++i) {
    const int rq = n0 + lg * 4 + i;
    if (rq >= N) continue;
    float* ob = out + ((size_t)b * N + rq) * C + h * DK + lr;
    ob[0] = (Oa[0][i] + Ob[0][i]) * invq[i];
    ob[16] = (Oa[1][i] + Ob[1][i]) * invq[i];
  }
}

// ---------------------------------------------------------------------------
extern "C" void kernel_launch(void* const* d_in, const int* in_sizes, int n_in,
                              void* d_out, int out_size, void* d_ws, size_t ws_size,
                              hipStream_t stream) {
  (void)in_sizes; (void)n_in; (void)out_size; (void)ws_size;
  const float* x     = (const float*)d_in[0];
  const float* Wq    = (const float*)d_in[1];
  const float* bq    = (const float*)d_in[2];
  const float* Wk    = (const float*)d_in[3];
  const float* bk    = (const float*)d_in[4];
  const float* Wv    = (const float*)d_in[5];
  const float* bv    = (const float*)d_in[6];
  const float* Wc    = (const float*)d_in[7];
  const float* bc    = (const float*)d_in[8];
  const float* gamma = (const float*)d_in[9];
  const float* beta  = (const float*)d_in[10];
  float* out = (float*)d_out;

  char* wsb = (char*)d_ws;
  // region0 (0..20.48MB): fp16 conv partials; dead after ln -> overlaid by qb/kb/vt
  ushort* xpart = (ushort*)wsb;
  ushort* qb = (ushort*)wsb;                       // 5,120,000 B
  ushort* kb = (ushort*)(wsb + 5120000);           // 2,560,000 B
  ushort* vt = (ushort*)(wsb + 7680000);           // 2,572,288 B (+4KB zero guard)
  char* p = wsb + 20480000;
  ushort* xTt  = (ushort*)p;                       // 5,144,576 B; dead after conv
  ushort* xr16 = (ushort*)p;                       // overlay (written at ln)
  p += 5144576;
  ushort* xb16 = (ushort*)p; p += 5120000;         // 5,120,000 B
  ushort* W16  = (ushort*)p;                       // 393,216 B
  // total = 31,137,792 B

  wcast<<<dim3(64, 3), 256, 0, stream>>>(Wq, Wk, Wv, W16);
  xt_cast<<<dim3((N + 63) / 64, C / 64, B), 256, 0, stream>>>(x, xTt, xb16);
  conv_mfma<<<dim3(MTILES * SPLIT), 256, 0, stream>>>(Wc, xTt, xpart);
  ln_kernel<<<dim3(B * M), 256, 0, stream>>>(xpart, bc, gamma, beta, xr16);
  // zero V^T (incl. pad + 4KB guard past the buffer for the tail-tile fragment overrun)
  (void)hipMemsetAsync(vt, 0, (size_t)B * H * DK * MP * 2 + 4096, stream);
  proj_all<<<dim3((B * N + 63) / 64, C / 64, 3), 256, 0, stream>>>(xb16, xr16, W16, bq, bk, bv,
                                                                   qb, kb, vt);
  attn7<<<dim3((N + 63) / 64, H, B), 256, 0, stream>>>(qb, kb, vt, out);
}

// Round 13
// 176.050 us; speedup vs baseline: 3.3492x; 1.4445x over previous
//
#include <hip/hip_runtime.h>
#include <hip/hip_bf16.h>
#include <hip/hip_fp16.h>
#include <math.h>

constexpr int B = 2;
constexpr int N = 5000;
constexpr int C = 256;
constexpr int H = 8;
constexpr int DK = 32;
constexpr int M = 2500;
constexpr int MP = 2512;            // padded V stride (16-elem multiple)
constexpr int KSTEPS = 157;         // ceil(5000/32)
constexpr int SPLIT = 8;            // conv split-K (== XCD count)
constexpr int MTILES = 79;          // ceil(2500/32)
constexpr float QSCALE = 0.2550598692503365f;        // (1/sqrt(32)) * log2(e)

typedef __attribute__((ext_vector_type(8))) short bf16x8;
typedef __attribute__((ext_vector_type(4))) float f32x4;

static __device__ __forceinline__ ushort f2bf(float f) {
  __hip_bfloat16 h = __float2bfloat16(f);
  return *reinterpret_cast<ushort*>(&h);
}

static __device__ __forceinline__ float fastexp2(float x) {
#if __has_builtin(__builtin_amdgcn_exp2f)
  return __builtin_amdgcn_exp2f(x);
#else
  return exp2f(x);
#endif
}

// ---------------------------------------------------------------------------
// K0a: cast Wq|Wk|Wv fp32 -> bf16 into W16[3][C][C]
// ---------------------------------------------------------------------------
__global__ __launch_bounds__(256) void wcast(const float* __restrict__ Wq,
                                             const float* __restrict__ Wk,
                                             const float* __restrict__ Wv,
                                             ushort* __restrict__ W16) {
  const float* src = (blockIdx.y == 0) ? Wq : (blockIdx.y == 1) ? Wk : Wv;
  const int idx = blockIdx.x * 1024 + threadIdx.x * 4;
  const float4 v = *reinterpret_cast<const float4*>(src + idx);
  ushort4 o;
  o.x = f2bf(v.x); o.y = f2bf(v.y); o.z = f2bf(v.z); o.w = f2bf(v.w);
  *reinterpret_cast<ushort4*>(W16 + (size_t)blockIdx.y * C * C + idx) = o;
}

// ---------------------------------------------------------------------------
// K0b: x fp32 -> xTt[b][ks][c][32] bf16 (k-step-blocked, zero pad) AND xb16[b][n][c]
// ---------------------------------------------------------------------------
__global__ __launch_bounds__(256) void xt_cast(const float* __restrict__ x,
                                               ushort* __restrict__ xTt,
                                               ushort* __restrict__ xb16) {
  const int n0 = blockIdx.x * 64, c0 = blockIdx.y * 64, b = blockIdx.z;
  const int tid = threadIdx.x;
  __shared__ ushort T[64][68];  // [n][c]
  const float* xb = x + (size_t)b * N * C;
#pragma unroll
  for (int i = 0; i < 4; ++i) {
    const int nl = (tid >> 4) + i * 16;
    const int cg = (tid & 15) * 4;
    float4 v = {0.f, 0.f, 0.f, 0.f};
    const bool ok = (n0 + nl) < N;
    if (ok) v = *reinterpret_cast<const float4*>(xb + (size_t)(n0 + nl) * C + c0 + cg);
    ushort4 u;
    u.x = f2bf(v.x); u.y = f2bf(v.y); u.z = f2bf(v.z); u.w = f2bf(v.w);
    T[nl][cg + 0] = u.x; T[nl][cg + 1] = u.y; T[nl][cg + 2] = u.z; T[nl][cg + 3] = u.w;
    if (ok)
      *reinterpret_cast<ushort4*>(xb16 + ((size_t)b * N + n0 + nl) * C + c0 + cg) = u;
  }
  __syncthreads();
  ushort* ob = xTt + (size_t)b * KSTEPS * C * 32;
  const int cl = tid & 63, ng = tid >> 6;
#pragma unroll
  for (int j = 0; j < 2; ++j) {
    const int nstart = ng * 16 + j * 8;   // 0,8,...,56
    const int n = n0 + nstart;
    if (n >= KSTEPS * 32) continue;
    const int ks = n >> 5, kk = n & 31;
    ushort vals[8];
#pragma unroll
    for (int jj = 0; jj < 8; ++jj) vals[jj] = T[nstart + jj][cl];
    *reinterpret_cast<bf16x8*>(ob + ((size_t)ks * C + (c0 + cl)) * 32 + kk) =
        *reinterpret_cast<const bf16x8*>(vals);
  }
}

// ---------------------------------------------------------------------------
// K1: conv via MFMA — coalesced direct-load, merged batch, XCD-affine split-K.
// ---------------------------------------------------------------------------
__global__ __launch_bounds__(256) void conv_mfma(const float* __restrict__ Wc,
                                                 const ushort* __restrict__ xTt,
                                                 ushort* __restrict__ xpart) {
  const int s = blockIdx.x & 7;
  const int mt = blockIdx.x >> 3;
  const int m0 = mt * 32;
  const int tid = threadIdx.x, w = tid >> 6, l = tid & 63;
  const int lr = l & 15, lg = l >> 4;
  f32x4 acc[16];
#pragma unroll
  for (int i = 0; i < 16; ++i) acc[i] = (f32x4){0.f, 0.f, 0.f, 0.f};
  const int row0 = m0 + lr, row1 = m0 + 16 + lr;
  const bool ok0 = row0 < M, ok1 = row1 < M;
  const float* ap0 = Wc + (size_t)(ok0 ? row0 : 0) * N + lg * 8;
  const float* ap1 = Wc + (size_t)(ok1 ? row1 : 0) * N + lg * 8;
  const int crow = w * 64 + lr;

#pragma unroll 2
  for (int ks = s; ks < KSTEPS; ks += SPLIT) {
    const int n0 = ks * 32;
    const bool kok = (n0 + lg * 8) < N;
    bf16x8 a0 = {0, 0, 0, 0, 0, 0, 0, 0}, a1 = {0, 0, 0, 0, 0, 0, 0, 0};
    if (ok0 && kok) {
      const float4 v0 = *reinterpret_cast<const float4*>(ap0 + n0);
      const float4 v1 = *reinterpret_cast<const float4*>(ap0 + n0 + 4);
      ushort u[8];
      u[0] = f2bf(v0.x); u[1] = f2bf(v0.y); u[2] = f2bf(v0.z); u[3] = f2bf(v0.w);
      u[4] = f2bf(v1.x); u[5] = f2bf(v1.y); u[6] = f2bf(v1.z); u[7] = f2bf(v1.w);
      a0 = *reinterpret_cast<const bf16x8*>(u);
    }
    if (ok1 && kok) {
      const float4 v0 = *reinterpret_cast<const float4*>(ap1 + n0);
      const float4 v1 = *reinterpret_cast<const float4*>(ap1 + n0 + 4);
      ushort u[8];
      u[0] = f2bf(v0.x); u[1] = f2bf(v0.y); u[2] = f2bf(v0.z); u[3] = f2bf(v0.w);
      u[4] = f2bf(v1.x); u[5] = f2bf(v1.y); u[6] = f2bf(v1.z); u[7] = f2bf(v1.w);
      a1 = *reinterpret_cast<const bf16x8*>(u);
    }
    bf16x8 bf[8];
#pragma unroll
    for (int ct = 0; ct < 4; ++ct)
#pragma unroll
      for (int bb = 0; bb < 2; ++bb)
        bf[ct * 2 + bb] = *reinterpret_cast<const bf16x8*>(
            xTt + (((size_t)bb * KSTEPS + ks) * C + crow + ct * 16) * 32 + lg * 8);
#pragma unroll
    for (int ct = 0; ct < 4; ++ct)
#pragma unroll
      for (int bb = 0; bb < 2; ++bb) {
        acc[(0 * 4 + ct) * 2 + bb] =
            __builtin_amdgcn_mfma_f32_16x16x32_bf16(a0, bf[ct * 2 + bb], acc[(0 * 4 + ct) * 2 + bb], 0, 0, 0);
        acc[(1 * 4 + ct) * 2 + bb] =
            __builtin_amdgcn_mfma_f32_16x16x32_bf16(a1, bf[ct * 2 + bb], acc[(1 * 4 + ct) * 2 + bb], 0, 0, 0);
      }
  }

#pragma unroll
  for (int mf = 0; mf < 2; ++mf)
#pragma unroll
    for (int ct = 0; ct < 4; ++ct)
#pragma unroll
      for (int bb = 0; bb < 2; ++bb)
#pragma unroll
        for (int i = 0; i < 4; ++i) {
          const int m = m0 + mf * 16 + lg * 4 + i;
          if (m < M) {
            const __half hv = __float2half(acc[(mf * 4 + ct) * 2 + bb][i]);
            xpart[(((size_t)s * B + bb) * M + m) * C + w * 64 + ct * 16 + lr] =
                *reinterpret_cast<const ushort*>(&hv);
          }
        }
}

// ---------------------------------------------------------------------------
// K2: sum SPLIT fp16 partials + bc + LayerNorm -> bf16 row-major xr16
// ---------------------------------------------------------------------------
__global__ __launch_bounds__(256) void ln_kernel(const ushort* __restrict__ xp,
                                                 const float* __restrict__ bc,
                                                 const float* __restrict__ gamma,
                                                 const float* __restrict__ beta,
                                                 ushort* __restrict__ xr16) {
  const int row = blockIdx.x;  // b*M + m
  const int tid = threadIdx.x;
  const int b = row / M, m = row - b * M;
  const size_t base = (size_t)row * C;
  float v = bc[m];
#pragma unroll
  for (int s = 0; s < SPLIT; ++s) {
    const ushort us = xp[(((size_t)s * B + b) * M + m) * C + tid];
    v += __half2float(*reinterpret_cast<const __half*>(&us));
  }
  __shared__ float red[8];
  float sum = v;
#pragma unroll
  for (int o = 32; o >= 1; o >>= 1) sum += __shfl_xor(sum, o);
  if ((tid & 63) == 0) red[tid >> 6] = sum;
  __syncthreads();
  const float mu = (red[0] + red[1] + red[2] + red[3]) * (1.f / C);
  const float d = v - mu;
  float s2 = d * d;
#pragma unroll
  for (int o = 32; o >= 1; o >>= 1) s2 += __shfl_xor(s2, o);
  if ((tid & 63) == 0) red[4 + (tid >> 6)] = s2;
  __syncthreads();
  const float var = (red[4] + red[5] + red[6] + red[7]) * (1.f / C);
  xr16[base + tid] = f2bf(gamma[tid] * d * rsqrtf(var + 1e-5f) + beta[tid]);
}

// ---------------------------------------------------------------------------
// K3: projections via MFMA. grid.z: 0=Q(xb16, scale=QSCALE incl log2e), 1=K(xr16),
// 2=V^T(xr16, bf16 d-major stride MP).
// ---------------------------------------------------------------------------
__global__ __launch_bounds__(256) void proj_all(const ushort* __restrict__ xb16,
                                                const ushort* __restrict__ xr16,
                                                const ushort* __restrict__ W16,
                                                const float* __restrict__ bq,
                                                const float* __restrict__ bk,
                                                const float* __restrict__ bv,
                                                ushort* __restrict__ qb,
                                                ushort* __restrict__ kb,
                                                ushort* __restrict__ vt) {
  const int z = blockIdx.z;
  const int R = (z == 0) ? N : M;
  const int totalRows = B * R;
  if (blockIdx.x * 64 >= totalRows) return;
  const ushort* xin = (z == 0) ? xb16 : xr16;
  const ushort* W = W16 + (size_t)z * C * C;
  const float* bias = (z == 0) ? bq : (z == 1) ? bk : bv;
  const int tid = threadIdx.x, w = tid >> 6, l = tid & 63;
  const int lr = l & 15, lg = l >> 4;
  const int r0 = blockIdx.x * 64 + w * 16;
  const int c0 = blockIdx.y * 64;
  const int arow = r0 + lr;
  const bool aok = arow < totalRows;
  f32x4 acc[4] = {{0.f,0.f,0.f,0.f},{0.f,0.f,0.f,0.f},{0.f,0.f,0.f,0.f},{0.f,0.f,0.f,0.f}};
#pragma unroll
  for (int ks = 0; ks < 8; ++ks) {
    bf16x8 af = {0, 0, 0, 0, 0, 0, 0, 0};
    if (aok) af = *reinterpret_cast<const bf16x8*>(xin + (size_t)arow * C + ks * 32 + lg * 8);
#pragma unroll
    for (int ct = 0; ct < 4; ++ct) {
      const bf16x8 bf =
          *reinterpret_cast<const bf16x8*>(W + (size_t)(c0 + ct * 16 + lr) * C + ks * 32 + lg * 8);
      acc[ct] = __builtin_amdgcn_mfma_f32_16x16x32_bf16(af, bf, acc[ct], 0, 0, 0);
    }
  }
#pragma unroll
  for (int ct = 0; ct < 4; ++ct) {
    const int c = c0 + ct * 16 + lr;
    const int h = c >> 5, d = c & 31;
    const float bi = bias[c];
#pragma unroll
    for (int i = 0; i < 4; ++i) {
      const int row = r0 + lg * 4 + i;
      if (row >= totalRows) continue;
      const int bb = (row >= R) ? 1 : 0;
      const int rr = row - bb * R;
      float val = acc[ct][i] + bi;
      if (z == 0) {
        val *= QSCALE;
        qb[(((size_t)bb * H + h) * N + rr) * DK + d] = f2bf(val);
      } else if (z == 1) {
        kb[(((size_t)bb * H + h) * M + rr) * DK + d] = f2bf(val);
      } else {
        vt[(((size_t)bb * H + h) * DK + d) * MP + rr] = f2bf(val);
      }
    }
  }
}

// ---------------------------------------------------------------------------
// K4: q-fattened flash attention. Each wave owns 32 q-rows (2 fragments), so
// every K/V fragment load is amortized over 2x output — total K/V load work
// (the measured invariant across R7/R8/R11/R12) halves. Swapped QK^T
// (mfma(K,Q)): lane owns q-row lr; scalar per-lane psum; exp2 (log2e folded
// into Q). P packed as uint2 into per-wave LDS [16][74] (word-stride 37 ≡ 5
// mod 32, coprime -> conflict-free writes AND b128 reads). In-kernel
// normalize. 40x8x2 = 640 blocks x 4 waves.
// ---------------------------------------------------------------------------
__global__ __launch_bounds__(256) void attn8(const ushort* __restrict__ q,
                                             const ushort* __restrict__ kk,
                                             const ushort* __restrict__ vt,
                                             float* __restrict__ out) {
  const int qt = blockIdx.x, h = blockIdx.y, b = blockIdx.z;
  const int tid = threadIdx.x, w = tid >> 6, l = tid & 63;
  const int lr = l & 15, lg = l >> 4;
  const int n0 = qt * 128 + w * 32;  // wave's 32 q-rows: frag0 = n0.., frag1 = n0+16..
  __shared__ ushort Plds[4][2][16][74];
  const ushort* qp = q + (size_t)(b * H + h) * N * DK;
  const ushort* kp = kk + (size_t)(b * H + h) * M * DK;
  const ushort* vp = vt + (size_t)(b * H + h) * DK * MP;

  bf16x8 qf0 = {0, 0, 0, 0, 0, 0, 0, 0}, qf1 = {0, 0, 0, 0, 0, 0, 0, 0};
  if (n0 + lr < N) qf0 = *reinterpret_cast<const bf16x8*>(qp + (size_t)(n0 + lr) * DK + lg * 8);
  if (n0 + 16 + lr < N)
    qf1 = *reinterpret_cast<const bf16x8*>(qp + (size_t)(n0 + 16 + lr) * DK + lg * 8);

  f32x4 O0[2] = {{0.f, 0.f, 0.f, 0.f}, {0.f, 0.f, 0.f, 0.f}};
  f32x4 O1[2] = {{0.f, 0.f, 0.f, 0.f}, {0.f, 0.f, 0.f, 0.f}};
  float ps0 = 0.f, ps1 = 0.f;

  constexpr int NT = (M + 63) / 64;  // 40 (39 full + masked tail handled uniformly)
#pragma unroll 1
  for (int t = 0; t < NT; ++t) {
    const int m0 = t * 64;
    const bool full = (m0 + 64) <= M;
    // ---- K fragments (shared by both q-frags) ----
    bf16x8 kf[4];
#pragma unroll
    for (int ct = 0; ct < 4; ++ct) {
      const int mr = m0 + ct * 16 + lr;
      if (full || mr < M)
        kf[ct] = *reinterpret_cast<const bf16x8*>(kp + (size_t)mr * DK + lg * 8);
      else
        kf[ct] = (bf16x8){0, 0, 0, 0, 0, 0, 0, 0};
    }
    // ---- V fragments (shared) ----
    bf16x8 vf[4];  // [dt][half]
#pragma unroll
    for (int dt = 0; dt < 2; ++dt) {
      const ushort* vb = vp + (size_t)(dt * 16 + lr) * MP + m0 + lg * 8;
      vf[dt * 2 + 0] = *reinterpret_cast<const bf16x8*>(vb);
      vf[dt * 2 + 1] = *reinterpret_cast<const bf16x8*>(vb + 32);
    }
    // ---- QK^T + softmax numerators for both q-frags ----
#pragma unroll
    for (int ct = 0; ct < 4; ++ct) {
      const f32x4 s0 =
          __builtin_amdgcn_mfma_f32_16x16x32_bf16(kf[ct], qf0, (f32x4){0.f, 0.f, 0.f, 0.f}, 0, 0, 0);
      const f32x4 s1 =
          __builtin_amdgcn_mfma_f32_16x16x32_bf16(kf[ct], qf1, (f32x4){0.f, 0.f, 0.f, 0.f}, 0, 0, 0);
      float p0[4], p1[4];
#pragma unroll
      for (int i = 0; i < 4; ++i) {
        const bool mok = full || (m0 + ct * 16 + lg * 4 + i) < M;
        p0[i] = mok ? fastexp2(s0[i]) : 0.f;
        p1[i] = mok ? fastexp2(s1[i]) : 0.f;
        ps0 += p0[i];
        ps1 += p1[i];
      }
      __hip_bfloat162 a01 = __float22bfloat162_rn(make_float2(p0[0], p0[1]));
      __hip_bfloat162 a23 = __float22bfloat162_rn(make_float2(p0[2], p0[3]));
      uint2 u0;
      u0.x = *reinterpret_cast<unsigned*>(&a01);
      u0.y = *reinterpret_cast<unsigned*>(&a23);
      *reinterpret_cast<uint2*>(&Plds[w][0][lr][ct * 16 + lg * 4]) = u0;
      __hip_bfloat162 b01 = __float22bfloat162_rn(make_float2(p1[0], p1[1]));
      __hip_bfloat162 b23 = __float22bfloat162_rn(make_float2(p1[2], p1[3]));
      uint2 u1;
      u1.x = *reinterpret_cast<unsigned*>(&b01);
      u1.y = *reinterpret_cast<unsigned*>(&b23);
      *reinterpret_cast<uint2*>(&Plds[w][1][lr][ct * 16 + lg * 4]) = u1;
    }
    // ---- PV for both q-frags (wave-private LDS; compiler inserts lgkmcnt) ----
    const bf16x8 pa00 = *reinterpret_cast<const bf16x8*>(&Plds[w][0][lr][lg * 8]);
    const bf16x8 pa01 = *reinterpret_cast<const bf16x8*>(&Plds[w][0][lr][32 + lg * 8]);
    const bf16x8 pa10 = *reinterpret_cast<const bf16x8*>(&Plds[w][1][lr][lg * 8]);
    const bf16x8 pa11 = *reinterpret_cast<const bf16x8*>(&Plds[w][1][lr][32 + lg * 8]);
#pragma unroll
    for (int dt = 0; dt < 2; ++dt) {
      O0[dt] = __builtin_amdgcn_mfma_f32_16x16x32_bf16(pa00, vf[dt * 2 + 0], O0[dt], 0, 0, 0);
      O0[dt] = __builtin_amdgcn_mfma_f32_16x16x32_bf16(pa01, vf[dt * 2 + 1], O0[dt], 0, 0, 0);
      O1[dt] = __builtin_amdgcn_mfma_f32_16x16x32_bf16(pa10, vf[dt * 2 + 0], O1[dt], 0, 0, 0);
      O1[dt] = __builtin_amdgcn_mfma_f32_16x16x32_bf16(pa11, vf[dt * 2 + 1], O1[dt], 0, 0, 0);
    }
  }

  // ---- normalize + write both q-frags ----
  ps0 += __shfl_xor(ps0, 16);
  ps0 += __shfl_xor(ps0, 32);
  ps1 += __shfl_xor(ps1, 16);
  ps1 += __shfl_xor(ps1, 32);
  const float inv0 = 1.f / ps0, inv1 = 1.f / ps1;
#pragma unroll
  for (int i = 0; i < 4; ++i) {
    const float iv0 = __shfl(inv0, lg * 4 + i);
    const float iv1 = __shfl(inv1, lg * 4 + i);
    const int r0q = n0 + lg * 4 + i;
    const int r1q = n0 + 16 + lg * 4 + i;
    if (r0q < N) {
      float* ob = out + ((size_t)b * N + r0q) * C + h * DK + lr;
      ob[0] = O0[0][i] * iv0;
      ob[16] = O0[1][i] * iv0;
    }
    if (r1q < N) {
      float* ob = out + ((size_t)b * N + r1q) * C + h * DK + lr;
      ob[0] = O1[0][i] * iv1;
      ob[16] = O1[1][i] * iv1;
    }
  }
}

// ---------------------------------------------------------------------------
extern "C" void kernel_launch(void* const* d_in, const int* in_sizes, int n_in,
                              void* d_out, int out_size, void* d_ws, size_t ws_size,
                              hipStream_t stream) {
  (void)in_sizes; (void)n_in; (void)out_size; (void)ws_size;
  const float* x     = (const float*)d_in[0];
  const float* Wq    = (const float*)d_in[1];
  const float* bq    = (const float*)d_in[2];
  const float* Wk    = (const float*)d_in[3];
  const float* bk    = (const float*)d_in[4];
  const float* Wv    = (const float*)d_in[5];
  const float* bv    = (const float*)d_in[6];
  const float* Wc    = (const float*)d_in[7];
  const float* bc    = (const float*)d_in[8];
  const float* gamma = (const float*)d_in[9];
  const float* beta  = (const float*)d_in[10];
  float* out = (float*)d_out;

  char* wsb = (char*)d_ws;
  // region0 (0..20.48MB): fp16 conv partials; dead after ln -> overlaid by qb/kb/vt
  ushort* xpart = (ushort*)wsb;
  ushort* qb = (ushort*)wsb;                       // 5,120,000 B
  ushort* kb = (ushort*)(wsb + 5120000);           // 2,560,000 B
  ushort* vt = (ushort*)(wsb + 7680000);           // 2,572,288 B (+4KB zero guard)
  char* p = wsb + 20480000;
  ushort* xTt  = (ushort*)p;                       // 5,144,576 B; dead after conv
  ushort* xr16 = (ushort*)p;                       // overlay (written at ln)
  p += 5144576;
  ushort* xb16 = (ushort*)p; p += 5120000;         // 5,120,000 B
  ushort* W16  = (ushort*)p;                       // 393,216 B
  // total = 31,137,792 B

  wcast<<<dim3(64, 3), 256, 0, stream>>>(Wq, Wk, Wv, W16);
  xt_cast<<<dim3((N + 63) / 64, C / 64, B), 256, 0, stream>>>(x, xTt, xb16);
  conv_mfma<<<dim3(MTILES * SPLIT), 256, 0, stream>>>(Wc, xTt, xpart);
  ln_kernel<<<dim3(B * M), 256, 0, stream>>>(xpart, bc, gamma, beta, xr16);
  // zero V^T pad region (+4KB guard) so tail-tile PV reads stay finite
  (void)hipMemsetAsync(vt, 0, (size_t)B * H * DK * MP * 2 + 4096, stream);
  proj_all<<<dim3((B * N + 63) / 64, C / 64, 3), 256, 0, stream>>>(xb16, xr16, W16, bq, bk, bv,
                                                                   qb, kb, vt);
  attn8<<<dim3((N + 127) / 128, H, B), 256, 0, stream>>>(qb, kb, vt, out);
}